// Round 1
// baseline (2168.516 us; speedup 1.0000x reference)
//
#include <hip/hip_runtime.h>
#include <cmath>

#define H 96
#define W 96
#define HW 9216
#define CIN 256
#define COUT 256
#define NB 4

// ---------------------------------------------------------------------------
// Kernel A: 27-channel offset conv (3x3, pad 1) -> py / px / sigmoid(mask)
// One thread per (n, k, h, w); w fastest => coalesced x reads.
// ---------------------------------------------------------------------------
__global__ __launch_bounds__(256)
void offset_conv_kernel(const float* __restrict__ x,
                        const float* __restrict__ w_off,
                        const float* __restrict__ b_off,
                        float* __restrict__ py,
                        float* __restrict__ px,
                        float* __restrict__ mk) {
  int gid = blockIdx.x * blockDim.x + threadIdx.x;
  const int total = NB * 27 * HW;
  if (gid >= total) return;
  int wv = gid % W;
  int h  = (gid / W) % H;
  int k  = (gid / HW) % 27;
  int n  = gid / (27 * HW);

  float acc = b_off[k];
  const float* xn = x + (size_t)n * CIN * HW;
  const float* wk = w_off + (size_t)k * CIN * 9;

  for (int c = 0; c < CIN; ++c) {
    const float* xc = xn + c * HW;
    const float* wc = wk + c * 9;
#pragma unroll
    for (int ty = 0; ty < 3; ++ty) {
      int iy = h + ty - 1;
      if (iy < 0 || iy >= H) continue;
#pragma unroll
      for (int tx = 0; tx < 3; ++tx) {
        int ix = wv + tx - 1;
        if (ix < 0 || ix >= W) continue;
        acc = fmaf(xc[iy * W + ix], wc[ty * 3 + tx], acc);
      }
    }
  }

  int hw = h * W + wv;
  if (k < 9) {
    int kyv = k / 3 - 1;
    py[(n * 9 + k) * HW + hw] = acc + (float)h + (float)kyv;
  } else if (k < 18) {
    int j = k - 9;
    int kxv = j % 3 - 1;
    px[(n * 9 + j) * HW + hw] = acc + (float)wv + (float)kxv;
  } else {
    mk[(n * 9 + (k - 18)) * HW + hw] = 1.0f / (1.0f + expf(-acc));
  }
}

// ---------------------------------------------------------------------------
// Kernel W: reorder w (Cout,Cin,3,3) -> wR[k][c][o] so GEMM tile loads are
// coalesced over o.
// ---------------------------------------------------------------------------
__global__ __launch_bounds__(256)
void w_reorder_kernel(const float* __restrict__ w, float* __restrict__ wR) {
  int gid = blockIdx.x * blockDim.x + threadIdx.x;
  const int total = 9 * CIN * COUT;
  if (gid >= total) return;
  int o = gid % COUT;
  int c = (gid / COUT) % CIN;
  int k = gid / (COUT * CIN);
  wR[gid] = w[(o * CIN + c) * 9 + k];
}

// ---------------------------------------------------------------------------
// Kernel B: fused bilinear-sample + GEMM.
// Block = [64 cout x 64 pixels] for one n. K loop: 9 taps x 16 c-chunks of 16.
// Per tap: 64 pixels' 4 corner indices + (mask-folded) weights computed once,
// reused across all 256 channels. acc = 4x4 registers/thread.
// Writes pre-BN y to out.
// ---------------------------------------------------------------------------
__global__ __launch_bounds__(256)
void main_conv_kernel(const float* __restrict__ x,
                      const float* __restrict__ wR,
                      const float* __restrict__ bias,
                      const float* __restrict__ py,
                      const float* __restrict__ px,
                      const float* __restrict__ mk,
                      float* __restrict__ out) {
  __shared__ int   sIdx[4][64];
  __shared__ float sWgt[4][64];
  __shared__ float samp[16][64];
  __shared__ float wT[16][64];

  int tid = threadIdx.x;
  int tx = tid & 15, ty = tid >> 4;
  int pixBase = blockIdx.x * 64;
  int oBase   = blockIdx.y * 64;
  int n       = blockIdx.z;

  float acc[4][4];
#pragma unroll
  for (int i = 0; i < 4; ++i)
#pragma unroll
    for (int j = 0; j < 4; ++j) acc[i][j] = 0.f;

  const float* xn = x + (size_t)n * CIN * HW;

  for (int k = 0; k < 9; ++k) {
    if (tid < 64) {
      int phw = pixBase + tid;
      int off = (n * 9 + k) * HW + phw;
      float fy = py[off], fx = px[off], fm = mk[off];
      float y0f = floorf(fy), x0f = floorf(fx);
      float ly = fy - y0f, lx = fx - x0f;
      int y0 = (int)y0f, x0 = (int)x0f;
      int cy0 = min(max(y0, 0), H - 1), cy1 = min(max(y0 + 1, 0), H - 1);
      int cx0 = min(max(x0, 0), W - 1), cx1 = min(max(x0 + 1, 0), W - 1);
      float vy0 = (y0 >= 0 && y0 <= H - 1) ? 1.f : 0.f;
      float vy1 = (y0 + 1 >= 0 && y0 + 1 <= H - 1) ? 1.f : 0.f;
      float vx0 = (x0 >= 0 && x0 <= W - 1) ? 1.f : 0.f;
      float vx1 = (x0 + 1 >= 0 && x0 + 1 <= W - 1) ? 1.f : 0.f;
      sIdx[0][tid] = cy0 * W + cx0;
      sIdx[1][tid] = cy0 * W + cx1;
      sIdx[2][tid] = cy1 * W + cx0;
      sIdx[3][tid] = cy1 * W + cx1;
      sWgt[0][tid] = (1.f - ly) * (1.f - lx) * fm * vy0 * vx0;
      sWgt[1][tid] = (1.f - ly) * lx * fm * vy0 * vx1;
      sWgt[2][tid] = ly * (1.f - lx) * fm * vy1 * vx0;
      sWgt[3][tid] = ly * lx * fm * vy1 * vx1;
    }
    __syncthreads();

    for (int cc = 0; cc < 16; ++cc) {
      // fill samp[16][64] (bilinear) and wT[16][64]
#pragma unroll
      for (int s = 0; s < 4; ++s) {
        int lin = tid + s * 256;
        int c_l = lin >> 6;
        int pix = lin & 63;
        int c = cc * 16 + c_l;
        const float* xc = xn + c * HW;
        int   i0 = sIdx[0][pix], i1 = sIdx[1][pix], i2 = sIdx[2][pix], i3 = sIdx[3][pix];
        float w0 = sWgt[0][pix], w1 = sWgt[1][pix], w2 = sWgt[2][pix], w3 = sWgt[3][pix];
        float v = 0.f;
        v = fmaf(xc[i0], w0, v);
        v = fmaf(xc[i1], w1, v);
        v = fmaf(xc[i2], w2, v);
        v = fmaf(xc[i3], w3, v);
        samp[c_l][pix] = v;
        wT[c_l][pix] = wR[((size_t)k * CIN + c) * COUT + oBase + pix];
      }
      __syncthreads();

#pragma unroll
      for (int c_l = 0; c_l < 16; ++c_l) {
        float a0 = wT[c_l][ty * 4 + 0];
        float a1 = wT[c_l][ty * 4 + 1];
        float a2 = wT[c_l][ty * 4 + 2];
        float a3 = wT[c_l][ty * 4 + 3];
        float b0 = samp[c_l][tx * 4 + 0];
        float b1 = samp[c_l][tx * 4 + 1];
        float b2 = samp[c_l][tx * 4 + 2];
        float b3 = samp[c_l][tx * 4 + 3];
        acc[0][0] = fmaf(a0, b0, acc[0][0]);
        acc[0][1] = fmaf(a0, b1, acc[0][1]);
        acc[0][2] = fmaf(a0, b2, acc[0][2]);
        acc[0][3] = fmaf(a0, b3, acc[0][3]);
        acc[1][0] = fmaf(a1, b0, acc[1][0]);
        acc[1][1] = fmaf(a1, b1, acc[1][1]);
        acc[1][2] = fmaf(a1, b2, acc[1][2]);
        acc[1][3] = fmaf(a1, b3, acc[1][3]);
        acc[2][0] = fmaf(a2, b0, acc[2][0]);
        acc[2][1] = fmaf(a2, b1, acc[2][1]);
        acc[2][2] = fmaf(a2, b2, acc[2][2]);
        acc[2][3] = fmaf(a2, b3, acc[2][3]);
        acc[3][0] = fmaf(a3, b0, acc[3][0]);
        acc[3][1] = fmaf(a3, b1, acc[3][1]);
        acc[3][2] = fmaf(a3, b2, acc[3][2]);
        acc[3][3] = fmaf(a3, b3, acc[3][3]);
      }
      __syncthreads();
    }
  }

#pragma unroll
  for (int i = 0; i < 4; ++i) {
    int o = oBase + ty * 4 + i;
    float bv = bias[o];
    float4 r;
    r.x = acc[i][0] + bv;
    r.y = acc[i][1] + bv;
    r.z = acc[i][2] + bv;
    r.w = acc[i][3] + bv;
    *(float4*)&out[(size_t)(n * COUT + o) * HW + pixBase + tx * 4] = r;
  }
}

// ---------------------------------------------------------------------------
// Kernel C: per-channel mean / inv-std over (N,H,W)
// ---------------------------------------------------------------------------
__global__ __launch_bounds__(256)
void bn_stats_kernel(const float* __restrict__ y,
                     float* __restrict__ meanArr, float* __restrict__ istdArr) {
  int o = blockIdx.x;
  int tid = threadIdx.x;
  float s = 0.f, q = 0.f;
  for (int n = 0; n < NB; ++n) {
    const float* p = y + (size_t)(n * COUT + o) * HW;
    for (int i = tid; i < HW; i += 256) {
      float v = p[i];
      s += v;
      q = fmaf(v, v, q);
    }
  }
#pragma unroll
  for (int d = 32; d > 0; d >>= 1) {
    s += __shfl_down(s, d, 64);
    q += __shfl_down(q, d, 64);
  }
  __shared__ float ss[4], qq[4];
  int wave = tid >> 6, lane = tid & 63;
  if (lane == 0) { ss[wave] = s; qq[wave] = q; }
  __syncthreads();
  if (tid == 0) {
    float S = ss[0] + ss[1] + ss[2] + ss[3];
    float Q = qq[0] + qq[1] + qq[2] + qq[3];
    const float inv = 1.f / (float)(NB * HW);
    float mean = S * inv;
    float var = Q * inv - mean * mean;
    meanArr[o] = mean;
    istdArr[o] = rsqrtf(var + 1e-5f);
  }
}

// ---------------------------------------------------------------------------
// Kernel D: in-place (y - mean) * istd * gamma + beta, ReLU; float4.
// ---------------------------------------------------------------------------
__global__ __launch_bounds__(256)
void bn_apply_kernel(float* __restrict__ y,
                     const float* __restrict__ meanArr,
                     const float* __restrict__ istdArr,
                     const float* __restrict__ gamma,
                     const float* __restrict__ beta) {
  int gid = blockIdx.x * blockDim.x + threadIdx.x;
  const int total4 = NB * COUT * HW / 4;
  if (gid >= total4) return;
  int o = ((gid * 4) / HW) % COUT;
  float scale = istdArr[o] * gamma[o];
  float shift = beta[o] - meanArr[o] * scale;
  float4 v = ((float4*)y)[gid];
  v.x = fmaxf(fmaf(v.x, scale, shift), 0.f);
  v.y = fmaxf(fmaf(v.y, scale, shift), 0.f);
  v.z = fmaxf(fmaf(v.z, scale, shift), 0.f);
  v.w = fmaxf(fmaf(v.w, scale, shift), 0.f);
  ((float4*)y)[gid] = v;
}

// ---------------------------------------------------------------------------
extern "C" void kernel_launch(void* const* d_in, const int* in_sizes, int n_in,
                              void* d_out, int out_size, void* d_ws, size_t ws_size,
                              hipStream_t stream) {
  const float* x     = (const float*)d_in[0];
  const float* w_off = (const float*)d_in[1];
  const float* b_off = (const float*)d_in[2];
  const float* w     = (const float*)d_in[3];
  const float* b     = (const float*)d_in[4];
  const float* gamma = (const float*)d_in[5];
  const float* beta  = (const float*)d_in[6];
  float* out = (float*)d_out;

  float* ws = (float*)d_ws;
  float* py = ws;                      // 4*9*9216 = 331776
  float* px = py + 331776;
  float* mk = px + 331776;
  float* wR = mk + 331776;             // 9*256*256 = 589824
  float* meanArr = wR + 589824;        // 256
  float* istdArr = meanArr + 256;      // 256

  offset_conv_kernel<<<(NB * 27 * HW) / 256, 256, 0, stream>>>(x, w_off, b_off, py, px, mk);
  w_reorder_kernel<<<(9 * CIN * COUT) / 256, 256, 0, stream>>>(w, wR);
  dim3 g(HW / 64, COUT / 64, NB);
  main_conv_kernel<<<g, 256, 0, stream>>>(x, wR, b, py, px, mk, out);
  bn_stats_kernel<<<COUT, 256, 0, stream>>>(out, meanArr, istdArr);
  bn_apply_kernel<<<(NB * COUT * HW / 4 + 255) / 256, 256, 0, stream>>>(out, meanArr, istdArr, gamma, beta);
}

// Round 2
// 668.029 us; speedup vs baseline: 3.2461x; 3.2461x over previous
//
#include <hip/hip_runtime.h>
#include <cmath>

#define H 96
#define W 96
#define HW 9216
#define CIN 256
#define COUT 256
#define NB 4
#define KTOT 2304  // 9*256

typedef float f32x4 __attribute__((ext_vector_type(4)));
typedef short bf16x8 __attribute__((ext_vector_type(8)));

__device__ __forceinline__ unsigned short f2bf(float f) {
  unsigned int u = __float_as_uint(f);
  u += 0x7fff + ((u >> 16) & 1);  // round-to-nearest-even
  return (unsigned short)(u >> 16);
}

// ---------------------------------------------------------------------------
// Offset conv, k-split 3-way: block = 256 pixels, one k-group (dy|dx|mask).
// Per c: 9 x-loads shared by 81 FMAs (9 outputs x 9 taps). Weights are
// wave-uniform -> scalar loads.
// ---------------------------------------------------------------------------
__global__ __launch_bounds__(256)
void offset_conv2(const float* __restrict__ x,
                  const float* __restrict__ w_off,
                  const float* __restrict__ b_off,
                  float* __restrict__ py,
                  float* __restrict__ px,
                  float* __restrict__ mk) {
  int tid = threadIdx.x;
  int hw = blockIdx.x * 256 + tid;
  int kg = blockIdx.y;  // 0: dy(k0..8)  1: dx(k9..17)  2: mask(k18..26)
  int n  = blockIdx.z;
  int h = hw / W, wv = hw % W;

  int   idx9[9];
  float m9[9];
#pragma unroll
  for (int ty = 0; ty < 3; ++ty) {
#pragma unroll
    for (int tx = 0; tx < 3; ++tx) {
      int iy = h + ty - 1, ix = wv + tx - 1;
      bool valid = (iy >= 0) && (iy < H) && (ix >= 0) && (ix < W);
      int iyc = min(max(iy, 0), H - 1), ixc = min(max(ix, 0), W - 1);
      idx9[ty * 3 + tx] = iyc * W + ixc;
      m9[ty * 3 + tx] = valid ? 1.f : 0.f;
    }
  }

  float acc[9];
#pragma unroll
  for (int kk = 0; kk < 9; ++kk) acc[kk] = b_off[kg * 9 + kk];

  const float* xn = x + (size_t)n * CIN * HW;
  const float* wbase = w_off + (size_t)(kg * 9) * CIN * 9;  // [kk][c][j]

  for (int c = 0; c < CIN; ++c) {
    const float* xc = xn + c * HW;
    float xv[9];
#pragma unroll
    for (int j = 0; j < 9; ++j) xv[j] = xc[idx9[j]] * m9[j];
#pragma unroll
    for (int kk = 0; kk < 9; ++kk) {
      const float* wr = wbase + (size_t)kk * CIN * 9 + c * 9;
#pragma unroll
      for (int j = 0; j < 9; ++j) acc[kk] = fmaf(xv[j], wr[j], acc[kk]);
    }
  }

  size_t off = (size_t)(n * 9) * HW + hw;
  if (kg == 0) {
#pragma unroll
    for (int kk = 0; kk < 9; ++kk)
      py[off + (size_t)kk * HW] = acc[kk] + (float)h + (float)(kk / 3 - 1);
  } else if (kg == 1) {
#pragma unroll
    for (int kk = 0; kk < 9; ++kk)
      px[off + (size_t)kk * HW] = acc[kk] + (float)wv + (float)(kk % 3 - 1);
  } else {
#pragma unroll
    for (int kk = 0; kk < 9; ++kk)
      mk[off + (size_t)kk * HW] = 1.f / (1.f + expf(-acc[kk]));
  }
}

// ---------------------------------------------------------------------------
// Weight convert/reorder: w (Cout,Cin,3,3) fp32 -> wB[o][k][c] bf16
// (kc = k*256+c is the GEMM K dim, c fastest)
// ---------------------------------------------------------------------------
__global__ __launch_bounds__(256)
void wb_convert(const float* __restrict__ w, unsigned short* __restrict__ wB) {
  int gid = blockIdx.x * 256 + threadIdx.x;
  int c = gid % CIN;
  int k = (gid / CIN) % 9;
  int o = gid / (CIN * 9);
  wB[gid] = f2bf(w[(size_t)(o * CIN + c) * 9 + k]);
}

// ---------------------------------------------------------------------------
// Main fused kernel: bilinear-sample -> bf16 -> LDS -> MFMA 16x16x32.
// Block = 512 thr (8 waves) = 256 couts x 64 pixels, one n.
// K loop: 9 taps x 8 chunks of 32 channels. Wave w owns o in [w*32,w*32+32).
// Epilogue: write pre-BN y + atomic per-channel sum/sumsq for BN.
// Bias b is skipped: it cancels exactly in (y - mean).
// ---------------------------------------------------------------------------
__global__ __launch_bounds__(512)
void main_conv_mfma(const float* __restrict__ x,
                    const unsigned short* __restrict__ wB,
                    const float* __restrict__ py,
                    const float* __restrict__ px,
                    const float* __restrict__ mk,
                    float* __restrict__ out,
                    float* __restrict__ sumArr,
                    float* __restrict__ sqArr) {
  __shared__ unsigned short sS[64 * 40];   // [pix][kc32 + pad8]
  __shared__ unsigned short sW[256 * 40];  // [o][kc32 + pad8]
  __shared__ int   sIdx[4][64];
  __shared__ float sWgt[4][64];

  int tid = threadIdx.x;
  int wv   = tid >> 6;        // wave 0..7
  int lane = tid & 63;
  int quad = lane >> 4;
  int l16  = lane & 15;
  int pixBase = blockIdx.x * 64;
  int n       = blockIdx.y;

  f32x4 acc[2][4];
#pragma unroll
  for (int i = 0; i < 2; ++i)
#pragma unroll
    for (int j = 0; j < 4; ++j) acc[i][j] = (f32x4){0.f, 0.f, 0.f, 0.f};

  const float* xn = x + (size_t)n * CIN * HW;

  for (int k = 0; k < 9; ++k) {
    if (tid < 64) {
      int off = (n * 9 + k) * HW + pixBase + tid;
      float fy = py[off], fx = px[off], fm = mk[off];
      float y0f = floorf(fy), x0f = floorf(fx);
      float ly = fy - y0f, lx = fx - x0f;
      int y0 = (int)y0f, x0 = (int)x0f;
      int cy0 = min(max(y0, 0), H - 1), cy1 = min(max(y0 + 1, 0), H - 1);
      int cx0 = min(max(x0, 0), W - 1), cx1 = min(max(x0 + 1, 0), W - 1);
      float vy0 = (y0 >= 0 && y0 <= H - 1) ? 1.f : 0.f;
      float vy1 = (y0 + 1 >= 0 && y0 + 1 <= H - 1) ? 1.f : 0.f;
      float vx0 = (x0 >= 0 && x0 <= W - 1) ? 1.f : 0.f;
      float vx1 = (x0 + 1 >= 0 && x0 + 1 <= W - 1) ? 1.f : 0.f;
      sIdx[0][tid] = cy0 * W + cx0;
      sIdx[1][tid] = cy0 * W + cx1;
      sIdx[2][tid] = cy1 * W + cx0;
      sIdx[3][tid] = cy1 * W + cx1;
      sWgt[0][tid] = (1.f - ly) * (1.f - lx) * fm * vy0 * vx0;
      sWgt[1][tid] = (1.f - ly) * lx * fm * vy0 * vx1;
      sWgt[2][tid] = ly * (1.f - lx) * fm * vy1 * vx0;
      sWgt[3][tid] = ly * lx * fm * vy1 * vx1;
    }
    __syncthreads();

    for (int cc = 0; cc < 8; ++cc) {
      // --- stage weights: sW[o][0..32) <- wB[o][k*256 + cc*32 ..] ---
#pragma unroll
      for (int r = 0; r < 2; ++r) {
        int id = tid + r * 512;        // 0..1024
        int o = id >> 2, part = id & 3;
        uint4 v = *(const uint4*)(wB + (size_t)o * KTOT + k * 256 + cc * 32 + part * 8);
        *(uint4*)(&sW[o * 40 + part * 8]) = v;
      }
      // --- stage samples: thread -> (pix = tid&63, c = cc*32 + 4q..4q+3) ---
      {
        int pix = tid & 63;
        int q = tid >> 6;
        int i0 = sIdx[0][pix], i1 = sIdx[1][pix], i2 = sIdx[2][pix], i3 = sIdx[3][pix];
        float w0 = sWgt[0][pix], w1 = sWgt[1][pix], w2 = sWgt[2][pix], w3 = sWgt[3][pix];
        unsigned short rbf[4];
#pragma unroll
        for (int j = 0; j < 4; ++j) {
          const float* xc = xn + (size_t)(cc * 32 + q * 4 + j) * HW;
          float v = xc[i0] * w0;
          v = fmaf(xc[i1], w1, v);
          v = fmaf(xc[i2], w2, v);
          v = fmaf(xc[i3], w3, v);
          rbf[j] = f2bf(v);
        }
        uint2 pk;
        pk.x = (unsigned int)rbf[0] | ((unsigned int)rbf[1] << 16);
        pk.y = (unsigned int)rbf[2] | ((unsigned int)rbf[3] << 16);
        *(uint2*)(&sS[pix * 40 + q * 4]) = pk;
      }
      __syncthreads();

      // --- MFMA: wave wv -> o tiles {wv*32, wv*32+16} x pix tiles {0,16,32,48}
      bf16x8 afrag[2];
#pragma unroll
      for (int ot = 0; ot < 2; ++ot) {
        int o = wv * 32 + ot * 16 + l16;
        afrag[ot] = *(const bf16x8*)(&sW[o * 40 + quad * 8]);
      }
#pragma unroll
      for (int pt = 0; pt < 4; ++pt) {
        int pix = pt * 16 + l16;
        bf16x8 bfrag = *(const bf16x8*)(&sS[pix * 40 + quad * 8]);
        acc[0][pt] = __builtin_amdgcn_mfma_f32_16x16x32_bf16(afrag[0], bfrag, acc[0][pt], 0, 0, 0);
        acc[1][pt] = __builtin_amdgcn_mfma_f32_16x16x32_bf16(afrag[1], bfrag, acc[1][pt], 0, 0, 0);
      }
      __syncthreads();
    }
  }

  // Epilogue: D layout col=lane&15 (pix), row=quad*4+reg (o within 16-tile)
#pragma unroll
  for (int ot = 0; ot < 2; ++ot) {
#pragma unroll
    for (int r = 0; r < 4; ++r) {
      int o = wv * 32 + ot * 16 + quad * 4 + r;
      float* rowp = out + (size_t)(n * COUT + o) * HW + pixBase;
      float s = 0.f, q = 0.f;
#pragma unroll
      for (int pt = 0; pt < 4; ++pt) {
        float v = acc[ot][pt][r];
        rowp[pt * 16 + l16] = v;
        s += v;
        q = fmaf(v, v, q);
      }
#pragma unroll
      for (int m = 8; m >= 1; m >>= 1) {
        s += __shfl_xor(s, m, 64);
        q += __shfl_xor(q, m, 64);
      }
      if (l16 == 0) {
        atomicAdd(&sumArr[o], s);
        atomicAdd(&sqArr[o], q);
      }
    }
  }
}

// ---------------------------------------------------------------------------
// BN finalize: per-channel scale/shift from atomics
// ---------------------------------------------------------------------------
__global__ __launch_bounds__(256)
void bn_finalize(const float* __restrict__ sumArr, const float* __restrict__ sqArr,
                 const float* __restrict__ gamma, const float* __restrict__ beta,
                 float* __restrict__ scaleArr, float* __restrict__ shiftArr) {
  int o = threadIdx.x;
  const float inv = 1.f / (float)(NB * HW);
  float mean = sumArr[o] * inv;
  float var = sqArr[o] * inv - mean * mean;
  float sc = rsqrtf(var + 1e-5f) * gamma[o];
  scaleArr[o] = sc;
  shiftArr[o] = beta[o] - mean * sc;
}

// ---------------------------------------------------------------------------
// BN apply + ReLU, in-place, float4
// ---------------------------------------------------------------------------
__global__ __launch_bounds__(256)
void bn_apply(float* __restrict__ y,
              const float* __restrict__ scaleArr,
              const float* __restrict__ shiftArr) {
  int gid = blockIdx.x * 256 + threadIdx.x;
  int o = ((gid * 4) / HW) % COUT;
  float scale = scaleArr[o], shift = shiftArr[o];
  float4 v = ((float4*)y)[gid];
  v.x = fmaxf(fmaf(v.x, scale, shift), 0.f);
  v.y = fmaxf(fmaf(v.y, scale, shift), 0.f);
  v.z = fmaxf(fmaf(v.z, scale, shift), 0.f);
  v.w = fmaxf(fmaf(v.w, scale, shift), 0.f);
  ((float4*)y)[gid] = v;
}

// ---------------------------------------------------------------------------
extern "C" void kernel_launch(void* const* d_in, const int* in_sizes, int n_in,
                              void* d_out, int out_size, void* d_ws, size_t ws_size,
                              hipStream_t stream) {
  const float* x     = (const float*)d_in[0];
  const float* w_off = (const float*)d_in[1];
  const float* b_off = (const float*)d_in[2];
  const float* w     = (const float*)d_in[3];
  // d_in[4] = b : skipped, cancels exactly in BN mean-subtraction
  const float* gamma = (const float*)d_in[5];
  const float* beta  = (const float*)d_in[6];
  float* out = (float*)d_out;

  float* ws = (float*)d_ws;
  float* py = ws;                         // 331776
  float* px = py + 331776;                // 331776
  float* mk = px + 331776;                // 331776
  unsigned short* wB = (unsigned short*)(mk + 331776);  // 589824 u16 = 294912 f
  float* sumArr   = (float*)(wB + 589824);  // 256
  float* sqArr    = sumArr + 256;           // 256
  float* scaleArr = sqArr + 256;            // 256
  float* shiftArr = scaleArr + 256;         // 256

  hipMemsetAsync(sumArr, 0, 512 * sizeof(float), stream);

  dim3 gOff(HW / 256, 3, NB);
  offset_conv2<<<gOff, 256, 0, stream>>>(x, w_off, b_off, py, px, mk);

  wb_convert<<<(COUT * KTOT) / 256, 256, 0, stream>>>(w, wB);

  dim3 gMain(HW / 64, NB);
  main_conv_mfma<<<gMain, 512, 0, stream>>>(x, wB, py, px, mk, out, sumArr, sqArr);

  bn_finalize<<<1, 256, 0, stream>>>(sumArr, sqArr, gamma, beta, scaleArr, shiftArr);

  bn_apply<<<(NB * COUT * HW / 4) / 256, 256, 0, stream>>>(out, scaleArr, shiftArr);
}